// Round 1
// baseline (291.642 us; speedup 1.0000x reference)
//
#include <hip/hip_runtime.h>
#include <hip/hip_bf16.h>
#include <stdint.h>

// Problem constants
#define B_ 4
#define T_ 4096
#define I_ 1024
#define H_ 16
#define D_ 64
#define M_TOT (B_*T_)      // 16384 rows (b*T+t)
#define N_TOT (H_*D_*2)    // 2048 cols (h*128 + d*2 + k2)
#define K_TOT I_           // 1024

typedef __bf16 bf16;
typedef __attribute__((ext_vector_type(8))) __bf16 bf16x8;
typedef __attribute__((ext_vector_type(4))) float f32x4;

#define AS_G __attribute__((address_space(1)))
#define AS_L __attribute__((address_space(3)))

__device__ __forceinline__ void gld_lds16(const void* g, void* l) {
    __builtin_amdgcn_global_load_lds((const AS_G void*)g, (AS_L void*)l, 16, 0, 0);
}

__device__ __forceinline__ float bflo(unsigned u){ union{unsigned x; float f;} c; c.x = u << 16; return c.f; }
__device__ __forceinline__ float bfhi(unsigned u){ union{unsigned x; float f;} c; c.x = u & 0xffff0000u; return c.f; }

// ---------------- pass 0a: X fp32 -> bf16 ----------------
__global__ void k_convert_x(const float* __restrict__ x, bf16* __restrict__ xb) {
    int idx = blockIdx.x * blockDim.x + threadIdx.x;
    int stride = gridDim.x * blockDim.x;
    const int n4 = (M_TOT * K_TOT) / 4;
    for (int i = idx; i < n4; i += stride) {
        float4 f = reinterpret_cast<const float4*>(x)[i];
        union { bf16 h[4]; uint64_t u; } pk;
        pk.h[0] = (bf16)f.x; pk.h[1] = (bf16)f.y; pk.h[2] = (bf16)f.z; pk.h[3] = (bf16)f.w;
        reinterpret_cast<uint64_t*>(xb)[i] = pk.u;
    }
}

// ---------------- pass 0b: W (I,N) fp32 -> Wt (N,I) bf16 (transpose) ----------------
__global__ void k_convert_wt(const float* __restrict__ w, bf16* __restrict__ wt) {
    __shared__ float tile[32][33];
    int tn = blockIdx.x % (N_TOT/32);   // 64 n-tiles
    int ti = blockIdx.x / (N_TOT/32);   // 32 i-tiles
    int tid = threadIdx.x;
    int c = tid & 31, rgrp = tid >> 5;  // 32 cols x 8 rows per pass
    #pragma unroll
    for (int p = 0; p < 4; ++p) {
        int il = p * 8 + rgrp;
        tile[il][c] = w[(ti*32 + il) * N_TOT + tn*32 + c];
    }
    __syncthreads();
    #pragma unroll
    for (int p = 0; p < 4; ++p) {
        int nl = p * 8 + rgrp;
        wt[(tn*32 + nl) * K_TOT + ti*32 + c] = (bf16)tile[c][nl];
    }
}

// ---------------- pass 1: GEMM kv = silu(X @ W), split into Kb (bf16) and V (fp32) ----------------
// Tile 128x128, BK=32, 4 waves (2x2), per-wave 64x64 = 4x4 frags of 16x16x32 MFMA.
__global__ void k_gemm(const bf16* __restrict__ xb, const bf16* __restrict__ wt,
                       bf16* __restrict__ kb, float* __restrict__ v) {
    __shared__ __attribute__((aligned(16))) bf16 As[2][128*32];
    __shared__ __attribute__((aligned(16))) bf16 Bs[2][128*32];
    const int tid = threadIdx.x;
    const int wid = tid >> 6, lane = tid & 63;
    const int wm = wid >> 1, wn = wid & 1;
    const int g = lane >> 4, r16 = lane & 15;
    const int bm = blockIdx.x >> 4, bn = blockIdx.x & 15;
    const int row0 = bm * 128;
    const int n0 = bn * 128;

    f32x4 acc[4][4];
    #pragma unroll
    for (int i=0;i<4;i++)
        #pragma unroll
        for(int j=0;j<4;j++) acc[i][j] = (f32x4){0.f,0.f,0.f,0.f};

    auto stage = [&](int buf, int ks) {
        int kk = ks * 32;
        #pragma unroll
        for (int j = 0; j < 2; ++j) {
            int c = j * 256 + tid;
            int row = c >> 2, kc = c & 3;
            gld_lds16(xb + (size_t)(row0 + row) * K_TOT + kk + kc * 8, &As[buf][c * 8]);
            gld_lds16(wt + (size_t)(n0  + row) * K_TOT + kk + kc * 8, &Bs[buf][c * 8]);
        }
    };

    stage(0, 0);
    __syncthreads();
    int buf = 0;
    for (int ks = 0; ks < 32; ++ks) {
        if (ks + 1 < 32) stage(buf ^ 1, ks + 1);
        bf16x8 af[4], bfr[4];
        #pragma unroll
        for (int mi = 0; mi < 4; ++mi)
            af[mi] = *reinterpret_cast<const bf16x8*>(&As[buf][(wm*64 + mi*16 + r16)*32 + g*8]);
        #pragma unroll
        for (int ni = 0; ni < 4; ++ni)
            bfr[ni] = *reinterpret_cast<const bf16x8*>(&Bs[buf][(wn*64 + ni*16 + r16)*32 + g*8]);
        #pragma unroll
        for (int mi = 0; mi < 4; ++mi)
            #pragma unroll
            for (int ni = 0; ni < 4; ++ni)
                acc[mi][ni] = __builtin_amdgcn_mfma_f32_16x16x32_bf16(af[mi], bfr[ni], acc[mi][ni], 0, 0, 0);
        __syncthreads();
        buf ^= 1;
    }

    // epilogue: silu, de-interleave k/v.  col within head = wn*64+ni*16+r16; d=col>>1, k2=col&1. h = bn.
    #pragma unroll
    for (int mi = 0; mi < 4; ++mi) {
      #pragma unroll
      for (int ni = 0; ni < 4; ++ni) {
        #pragma unroll
        for (int r = 0; r < 4; ++r) {
            int row = row0 + wm*64 + mi*16 + g*4 + r;
            int col = wn*64 + ni*16 + r16;
            int d = col >> 1, k2 = col & 1;
            float val = acc[mi][ni][r];
            float sg = 1.0f / (1.0f + __expf(-val));
            val = val * sg;
            size_t addr = (size_t)row * (H_*D_) + bn * D_ + d;
            if (k2 == 0) kb[addr] = (bf16)val;
            else         v[addr]  = val;
        }
      }
    }
}

// ---------------- pass 2: s[r,h] = sum_d q[h,d]*k[r,h,d] ----------------
__global__ void k_score(const bf16* __restrict__ kb, const float* __restrict__ q, float* __restrict__ s) {
    int idx = blockIdx.x * 256 + threadIdx.x;  // 0..M_TOT*H_-1
    int h = idx & (H_-1), r = idx >> 4;
    const uint4* k4  = reinterpret_cast<const uint4*>(kb + (size_t)r * (H_*D_) + h * D_);
    const float4* q4 = reinterpret_cast<const float4*>(q + h * D_);
    float acc = 0.f;
    #pragma unroll
    for (int j = 0; j < 8; ++j) {
        uint4 pk = k4[j];
        float4 qa = q4[2*j], qb = q4[2*j+1];
        acc += qa.x*bflo(pk.x) + qa.y*bfhi(pk.x) + qa.z*bflo(pk.y) + qa.w*bfhi(pk.y);
        acc += qb.x*bflo(pk.z) + qb.y*bfhi(pk.z) + qb.z*bflo(pk.w) + qb.w*bfhi(pk.w);
    }
    s[idx] = acc;
}

// ---------------- scan: 64 chunks of 64 per (b,h); one wave per chunk, lane = d ----------------
// Phase A: chunk aggregates (m,u,w[64]) -> agg[C*66]
__global__ void k_scanA(const float* __restrict__ s, const float* __restrict__ v, float* __restrict__ agg) {
    int C = blockIdx.x * 4 + (threadIdx.x >> 6);
    int lane = threadIdx.x & 63;
    int p = C >> 6, c = C & 63;
    int b = p >> 4, h = p & 15;
    int rbase = b * T_ + c * 64;
    float m = -INFINITY, u = 0.f, w = 0.f;
    for (int i = 0; i < 64; ++i) {
        int r = rbase + i;
        float sv = s[r * H_ + h];
        float vv = v[(size_t)r * (H_*D_) + h * D_ + lane];
        float mn = fmaxf(m, sv);
        float ea = __expf(m - mn);
        float eb = __expf(sv - mn);
        u = u * ea + eb;
        w = w * ea + vv * eb;
        m = mn;
    }
    float* a = agg + C * 66;
    if (lane == 0) { a[0] = m; a[1] = u; }
    a[2 + lane] = w;
}

// Phase B: exclusive scan over the 64 chunk aggregates for each (b,h) pair
__global__ void k_scanB(const float* __restrict__ agg, float* __restrict__ pre) {
    int p = blockIdx.x;       // 0..63
    int lane = threadIdx.x;   // 0..63
    float m = -INFINITY, u = 0.f, w = 0.f;
    for (int c = 0; c < 64; ++c) {
        int idx = (p * 64 + c) * 66;
        float* o = pre + idx;
        if (lane == 0) { o[0] = m; o[1] = u; }
        o[2 + lane] = w;
        float ma = agg[idx], ua = agg[idx + 1], wa = agg[idx + 2 + lane];
        float mn = fmaxf(m, ma);
        float ec = __expf(m - mn), ea = __expf(ma - mn);
        u = u * ec + ua * ea;
        w = w * ec + wa * ea;
        m = mn;
    }
}

// Phase C: local rescan with carry-in; emit out = w/u per t
__global__ void k_scanC(const float* __restrict__ s, const float* __restrict__ v,
                        const float* __restrict__ pre, float* __restrict__ out) {
    int C = blockIdx.x * 4 + (threadIdx.x >> 6);
    int lane = threadIdx.x & 63;
    int p = C >> 6, c = C & 63;
    int b = p >> 4, h = p & 15;
    int rbase = b * T_ + c * 64;
    const float* pr = pre + C * 66;
    float m = pr[0], u = pr[1], w = pr[2 + lane];
    for (int i = 0; i < 64; ++i) {
        int r = rbase + i;
        float sv = s[r * H_ + h];
        float vv = v[(size_t)r * (H_*D_) + h * D_ + lane];
        float mn = fmaxf(m, sv);
        float ea = __expf(m - mn);
        float eb = __expf(sv - mn);
        u = u * ea + eb;
        w = w * ea + vv * eb;
        m = mn;
        out[(size_t)r * (H_*D_) + h * D_ + lane] = __fdividef(w, u);
    }
}

extern "C" void kernel_launch(void* const* d_in, const int* in_sizes, int n_in,
                              void* d_out, int out_size, void* d_ws, size_t ws_size,
                              hipStream_t stream) {
    (void)in_sizes; (void)n_in; (void)out_size; (void)ws_size;
    const float* x  = (const float*)d_in[0];
    const float* wk = (const float*)d_in[1];
    const float* qk = (const float*)d_in[2];
    float* out = (float*)d_out;
    char* ws = (char*)d_ws;

    // workspace layout (bytes)
    bf16*  xb  = (bf16*) (ws);                         // 16384*1024*2  = 33,554,432
    bf16*  wt  = (bf16*) (ws + 33554432ull);           //  2048*1024*2  =  4,194,304
    bf16*  kb  = (bf16*) (ws + 37748736ull);           // 16384*1024*2  = 33,554,432
    float* v   = (float*)(ws + 71303168ull);           // 16384*1024*4  = 67,108,864
    float* s   = (float*)(ws + 138412032ull);          // 16384*16*4    =  1,048,576
    float* agg = (float*)(ws + 139460608ull);          // 4096*66*4     =  1,081,344
    float* pre = (float*)(ws + 140541952ull);          // 4096*66*4     =  1,081,344
                                                       // total ~141.6 MB

    hipLaunchKernelGGL(k_convert_x,  dim3(2048), dim3(256), 0, stream, x, xb);
    hipLaunchKernelGGL(k_convert_wt, dim3(2048), dim3(256), 0, stream, wk, wt);
    hipLaunchKernelGGL(k_gemm,       dim3((M_TOT/128)*(N_TOT/128)), dim3(256), 0, stream, xb, wt, kb, v);
    hipLaunchKernelGGL(k_score,      dim3(M_TOT*H_/256), dim3(256), 0, stream, kb, qk, s);
    hipLaunchKernelGGL(k_scanA,      dim3(B_*H_*64/4), dim3(256), 0, stream, s, v, agg);
    hipLaunchKernelGGL(k_scanB,      dim3(B_*H_), dim3(64), 0, stream, agg, pre);
    hipLaunchKernelGGL(k_scanC,      dim3(B_*H_*64/4), dim3(256), 0, stream, s, v, pre, out);
}

// Round 2
// 256.460 us; speedup vs baseline: 1.1372x; 1.1372x over previous
//
#include <hip/hip_runtime.h>
#include <hip/hip_bf16.h>
#include <stdint.h>

// Problem constants
#define B_ 4
#define T_ 4096
#define I_ 1024
#define H_ 16
#define D_ 64
#define M_TOT (B_*T_)      // 16384
#define N_TOT (H_*D_*2)    // 2048, permuted layout: col = h*128 + k2*64 + d
#define K_TOT I_           // 1024

#define BM 256
#define BN 256
#define BK 64
#define NT (K_TOT/BK)      // 16

typedef __bf16 bf16;
typedef __attribute__((ext_vector_type(8))) __bf16 bf16x8;
typedef __attribute__((ext_vector_type(4))) float f32x4;

#define AS_G __attribute__((address_space(1)))
#define AS_L __attribute__((address_space(3)))

__device__ __forceinline__ void gld_lds16(const void* g, void* l) {
    __builtin_amdgcn_global_load_lds((const AS_G void*)g, (AS_L void*)l, 16, 0, 0);
}

// ---------------- pass 0: fused convert: X fp32->bf16 ; W (I,N) -> Wt (N',I) bf16 permuted ----------------
__global__ void k_prep(const float* __restrict__ x, const float* __restrict__ w,
                       bf16* __restrict__ xb, bf16* __restrict__ wt) {
    if (blockIdx.x < 2048) {
        int idx = blockIdx.x * 256 + threadIdx.x;
        const int n4 = (M_TOT * K_TOT) / 4;
        for (int i = idx; i < n4; i += 2048 * 256) {
            float4 f = reinterpret_cast<const float4*>(x)[i];
            union { bf16 h[4]; uint64_t u; } pk;
            pk.h[0] = (bf16)f.x; pk.h[1] = (bf16)f.y; pk.h[2] = (bf16)f.z; pk.h[3] = (bf16)f.w;
            reinterpret_cast<uint64_t*>(xb)[i] = pk.u;
        }
    } else {
        __shared__ float tile[32][33];
        int bid = blockIdx.x - 2048;
        int tn = bid % (N_TOT/32);   // 64 col-tiles
        int ti = bid / (N_TOT/32);   // 32 i-tiles
        int tid = threadIdx.x;
        int c = tid & 31, rgrp = tid >> 5;
        #pragma unroll
        for (int p = 0; p < 4; ++p) {
            int il = p * 8 + rgrp;
            int cn = tn*32 + c;                      // permuted output col
            int h = cn >> 7, k2 = (cn >> 6) & 1, d = cn & 63;
            int nsrc = (h << 7) + (d << 1) + k2;     // original col
            tile[il][c] = w[(ti*32 + il) * N_TOT + nsrc];
        }
        __syncthreads();
        #pragma unroll
        for (int p = 0; p < 4; ++p) {
            int nl = p * 8 + rgrp;
            wt[(size_t)(tn*32 + nl) * K_TOT + ti*32 + c] = (bf16)tile[c][nl];
        }
    }
}

// ---------------- pass 1: GEMM kv = silu(X @ W) -> bf16 kv[row][2048] (k: +0..63, v: +64..127 per head) ----
// 256x256 tile, BK=64, 8 waves (2M x 4N), per-wave 128x64, phase-split schedule.
// LDS swizzle: 16B slot s of row r stored at slot s^(r&7); staged via pre-swizzled global source.
__device__ __forceinline__ void stage_tile(const bf16* __restrict__ src, bf16* dst,
                                           int row0, int k0, int tid) {
    #pragma unroll
    for (int j = 0; j < 4; ++j) {
        int c = j * 512 + tid;
        int row = c >> 3, p = c & 7;
        gld_lds16(src + (size_t)(row0 + row) * K_TOT + k0 + ((p ^ (row & 7)) << 3),
                  dst + c * 8);
    }
}

__device__ __forceinline__ bf16x8 frag(const bf16* base, int row, int slot) {
    const char* p = (const char*)base + row * 128 + (((slot ^ (row & 7)) & 7) << 4);
    return *reinterpret_cast<const bf16x8*>(p);
}

__global__ __launch_bounds__(512, 2)
void k_gemm(const bf16* __restrict__ xb, const bf16* __restrict__ wt,
            bf16* __restrict__ kv) {
    extern __shared__ __attribute__((aligned(16))) char smem[];
    bf16* As = (bf16*)smem;            // [2][256*64]
    bf16* Bs = (bf16*)(smem + 65536);  // [2][256*64]

    const int tid = threadIdx.x;
    const int wid = tid >> 6, lane = tid & 63;
    const int wm = wid >> 2, wn = wid & 3;
    const int g = lane >> 4, r16 = lane & 15;

    // XCD-aware swizzle: 512 blocks, 8 XCDs, 64 contiguous per XCD
    int bid = blockIdx.x;
    int swz = (bid & 7) * 64 + (bid >> 3);
    int bm = swz >> 3, bn = swz & 7;   // 64 x 8
    const int row0 = bm * BM, n0 = bn * BN;

    f32x4 acc[8][4];
    #pragma unroll
    for (int i = 0; i < 8; ++i)
        #pragma unroll
        for (int j = 0; j < 4; ++j) acc[i][j] = (f32x4){0.f,0.f,0.f,0.f};

    stage_tile(xb, As, row0, 0, tid);
    stage_tile(wt, Bs, n0, 0, tid);
    asm volatile("s_waitcnt vmcnt(0)" ::: "memory");
    __builtin_amdgcn_s_barrier();

    for (int t = 0; t < NT; ++t) {
        const int buf = t & 1;
        const bf16* Ab = As + buf * (BM*BK);
        const bf16* Bb = Bs + buf * (BN*BK);
        bf16* An = As + (buf^1) * (BM*BK);
        bf16* Bn = Bs + (buf^1) * (BN*BK);
        const bool pf = (t + 1 < NT);
        bf16x8 a[4], b[4];

        // ---- P0: ks=0, mi 0-3 ----
        #pragma unroll
        for (int mi = 0; mi < 4; ++mi) a[mi] = frag(Ab, wm*128 + mi*16 + r16, g);
        #pragma unroll
        for (int ni = 0; ni < 4; ++ni) b[ni] = frag(Bb, wn*64 + ni*16 + r16, g);
        if (pf) stage_tile(xb, An, row0, (t+1)*BK, tid);
        __builtin_amdgcn_s_barrier();
        __builtin_amdgcn_s_setprio(1);
        #pragma unroll
        for (int mi = 0; mi < 4; ++mi)
            #pragma unroll
            for (int ni = 0; ni < 4; ++ni)
                acc[mi][ni] = __builtin_amdgcn_mfma_f32_16x16x32_bf16(a[mi], b[ni], acc[mi][ni], 0,0,0);
        __builtin_amdgcn_s_setprio(0);
        __builtin_amdgcn_s_barrier();

        // ---- P1: ks=0, mi 4-7 (b reused) ----
        #pragma unroll
        for (int mi = 0; mi < 4; ++mi) a[mi] = frag(Ab, wm*128 + (mi+4)*16 + r16, g);
        if (pf) stage_tile(wt, Bn, n0, (t+1)*BK, tid);
        __builtin_amdgcn_s_barrier();
        __builtin_amdgcn_s_setprio(1);
        #pragma unroll
        for (int mi = 0; mi < 4; ++mi)
            #pragma unroll
            for (int ni = 0; ni < 4; ++ni)
                acc[mi+4][ni] = __builtin_amdgcn_mfma_f32_16x16x32_bf16(a[mi], b[ni], acc[mi+4][ni], 0,0,0);
        __builtin_amdgcn_s_setprio(0);
        __builtin_amdgcn_s_barrier();

        // ---- P2: ks=1, mi 0-3 ----
        #pragma unroll
        for (int mi = 0; mi < 4; ++mi) a[mi] = frag(Ab, wm*128 + mi*16 + r16, 4 + g);
        #pragma unroll
        for (int ni = 0; ni < 4; ++ni) b[ni] = frag(Bb, wn*64 + ni*16 + r16, 4 + g);
        __builtin_amdgcn_s_barrier();
        __builtin_amdgcn_s_setprio(1);
        #pragma unroll
        for (int mi = 0; mi < 4; ++mi)
            #pragma unroll
            for (int ni = 0; ni < 4; ++ni)
                acc[mi][ni] = __builtin_amdgcn_mfma_f32_16x16x32_bf16(a[mi], b[ni], acc[mi][ni], 0,0,0);
        __builtin_amdgcn_s_setprio(0);
        __builtin_amdgcn_s_barrier();

        // ---- P3: ks=1, mi 4-7 ----
        #pragma unroll
        for (int mi = 0; mi < 4; ++mi) a[mi] = frag(Ab, wm*128 + (mi+4)*16 + r16, 4 + g);
        __builtin_amdgcn_s_barrier();
        __builtin_amdgcn_s_setprio(1);
        #pragma unroll
        for (int mi = 0; mi < 4; ++mi)
            #pragma unroll
            for (int ni = 0; ni < 4; ++ni)
                acc[mi+4][ni] = __builtin_amdgcn_mfma_f32_16x16x32_bf16(a[mi], b[ni], acc[mi+4][ni], 0,0,0);
        __builtin_amdgcn_s_setprio(0);
        if (pf) asm volatile("s_waitcnt vmcnt(0)" ::: "memory");
        __builtin_amdgcn_s_barrier();
    }

    // epilogue: silu, store bf16 to kv[row][col], col already k/v-split per head
    #pragma unroll
    for (int mi = 0; mi < 8; ++mi) {
      #pragma unroll
      for (int ni = 0; ni < 4; ++ni) {
        #pragma unroll
        for (int r = 0; r < 4; ++r) {
            int row = row0 + wm*128 + mi*16 + g*4 + r;
            int col = n0 + wn*64 + ni*16 + r16;
            float val = acc[mi][ni][r];
            val = val / (1.0f + __expf(-val));
            kv[(size_t)row * N_TOT + col] = (bf16)val;
        }
      }
    }
}

__device__ __forceinline__ float bflo(unsigned u){ union{unsigned x; float f;} c; c.x = u << 16; return c.f; }
__device__ __forceinline__ float bfhi(unsigned u){ union{unsigned x; float f;} c; c.x = u & 0xffff0000u; return c.f; }

// ---------------- pass 2: s[r,h] = sum_d q[h,d]*k[r,h,d] ----------------
__global__ void k_score(const bf16* __restrict__ kv, const float* __restrict__ q, float* __restrict__ s) {
    int idx = blockIdx.x * 256 + threadIdx.x;
    int h = idx & (H_-1), r = idx >> 4;
    const uint4* k4  = reinterpret_cast<const uint4*>(kv + (size_t)r * N_TOT + h * 128);
    const float4* q4 = reinterpret_cast<const float4*>(q + h * D_);
    float acc = 0.f;
    #pragma unroll
    for (int j = 0; j < 8; ++j) {
        uint4 pk = k4[j];
        float4 qa = q4[2*j], qb = q4[2*j+1];
        acc += qa.x*bflo(pk.x) + qa.y*bfhi(pk.x) + qa.z*bflo(pk.y) + qa.w*bfhi(pk.y);
        acc += qb.x*bflo(pk.z) + qb.y*bfhi(pk.z) + qb.z*bflo(pk.w) + qb.w*bfhi(pk.w);
    }
    s[idx] = acc;
}

// ---------------- scan: 64 chunks of 64 per (b,h); one wave per chunk, lane = d ----------------
__global__ void k_scanA(const float* __restrict__ s, const bf16* __restrict__ kv, float* __restrict__ agg) {
    int C = blockIdx.x * 4 + (threadIdx.x >> 6);
    int lane = threadIdx.x & 63;
    int p = C >> 6, c = C & 63;
    int b = p >> 4, h = p & 15;
    int rbase = b * T_ + c * 64;
    const bf16* vbase = kv + h * 128 + 64 + lane;
    float m = -INFINITY, u = 0.f, w = 0.f;
    #pragma unroll 4
    for (int i = 0; i < 64; ++i) {
        int r = rbase + i;
        float sv = s[r * H_ + h];
        float vv = (float)vbase[(size_t)r * N_TOT];
        float mn = fmaxf(m, sv);
        float ea = __expf(m - mn);
        float eb = __expf(sv - mn);
        u = u * ea + eb;
        w = w * ea + vv * eb;
        m = mn;
    }
    float* a = agg + C * 66;
    if (lane == 0) { a[0] = m; a[1] = u; }
    a[2 + lane] = w;
}

__global__ void k_scanB(const float* __restrict__ agg, float* __restrict__ pre) {
    int p = blockIdx.x;
    int lane = threadIdx.x;
    float m = -INFINITY, u = 0.f, w = 0.f;
    for (int c = 0; c < 64; ++c) {
        int idx = (p * 64 + c) * 66;
        float* o = pre + idx;
        if (lane == 0) { o[0] = m; o[1] = u; }
        o[2 + lane] = w;
        float ma = agg[idx], ua = agg[idx + 1], wa = agg[idx + 2 + lane];
        float mn = fmaxf(m, ma);
        float ec = __expf(m - mn), ea = __expf(ma - mn);
        u = u * ec + ua * ea;
        w = w * ec + wa * ea;
        m = mn;
    }
}

__global__ void k_scanC(const float* __restrict__ s, const bf16* __restrict__ kv,
                        const float* __restrict__ pre, float* __restrict__ out) {
    int C = blockIdx.x * 4 + (threadIdx.x >> 6);
    int lane = threadIdx.x & 63;
    int p = C >> 6, c = C & 63;
    int b = p >> 4, h = p & 15;
    int rbase = b * T_ + c * 64;
    const bf16* vbase = kv + h * 128 + 64 + lane;
    const float* pr = pre + C * 66;
    float m = pr[0], u = pr[1], w = pr[2 + lane];
    #pragma unroll 4
    for (int i = 0; i < 64; ++i) {
        int r = rbase + i;
        float sv = s[r * H_ + h];
        float vv = (float)vbase[(size_t)r * N_TOT];
        float mn = fmaxf(m, sv);
        float ea = __expf(m - mn);
        float eb = __expf(sv - mn);
        u = u * ea + eb;
        w = w * ea + vv * eb;
        m = mn;
        out[(size_t)r * (H_*D_) + h * D_ + lane] = __fdividef(w, u);
    }
}

extern "C" void kernel_launch(void* const* d_in, const int* in_sizes, int n_in,
                              void* d_out, int out_size, void* d_ws, size_t ws_size,
                              hipStream_t stream) {
    (void)in_sizes; (void)n_in; (void)out_size; (void)ws_size;
    const float* x  = (const float*)d_in[0];
    const float* wk = (const float*)d_in[1];
    const float* qk = (const float*)d_in[2];
    float* out = (float*)d_out;
    char* ws = (char*)d_ws;

    bf16*  xb  = (bf16*) (ws);                      // 33,554,432
    bf16*  wt  = (bf16*) (ws + 33554432ull);        //  4,194,304
    bf16*  kv  = (bf16*) (ws + 37748736ull);        // 67,108,864
    float* s   = (float*)(ws + 104857600ull);       //  1,048,576
    float* agg = (float*)(ws + 105906176ull);       //  1,081,344
    float* pre = (float*)(ws + 106987520ull);       //  1,081,344

    hipLaunchKernelGGL(k_prep,  dim3(4096), dim3(256), 0, stream, x, wk, xb, wt);
    hipLaunchKernelGGL(k_gemm,  dim3(512), dim3(512), 131072, stream, xb, wt, kv);
    hipLaunchKernelGGL(k_score, dim3(M_TOT*H_/256), dim3(256), 0, stream, kv, qk, s);
    hipLaunchKernelGGL(k_scanA, dim3(B_*H_*64/4), dim3(256), 0, stream, s, kv, agg);
    hipLaunchKernelGGL(k_scanB, dim3(B_*H_), dim3(64), 0, stream, agg, pre);
    hipLaunchKernelGGL(k_scanC, dim3(B_*H_*64/4), dim3(256), 0, stream, s, kv, pre, out);
}

// Round 3
// 243.274 us; speedup vs baseline: 1.1988x; 1.0542x over previous
//
#include <hip/hip_runtime.h>
#include <hip/hip_bf16.h>
#include <stdint.h>

// Problem constants
#define B_ 4
#define T_ 4096
#define I_ 1024
#define H_ 16
#define D_ 64
#define M_TOT (B_*T_)      // 16384
#define N_TOT (H_*D_*2)    // 2048, permuted: col = h*128 + k2*64 + d
#define K_TOT I_           // 1024

#define BM 256
#define BN 128
#define BK 64
#define NT (K_TOT/BK)      // 16
#define BUF_ELEMS (BM*BK + BN*BK)   // 24576 elems (A 32KB + B 16KB)

typedef __bf16 bf16;
typedef __attribute__((ext_vector_type(8))) __bf16 bf16x8;
typedef __attribute__((ext_vector_type(4))) float f32x4;

#define AS_G __attribute__((address_space(1)))
#define AS_L __attribute__((address_space(3)))

__device__ __forceinline__ void gld_lds16(const void* g, void* l) {
    __builtin_amdgcn_global_load_lds((const AS_G void*)g, (AS_L void*)l, 16, 0, 0);
}

// ---------------- pass 0: fused convert: X fp32->bf16 ; W (I,N) -> Wt (N',I) bf16 permuted ----------------
__global__ void k_prep(const float* __restrict__ x, const float* __restrict__ w,
                       bf16* __restrict__ xb, bf16* __restrict__ wt) {
    if (blockIdx.x < 2048) {
        int idx = blockIdx.x * 256 + threadIdx.x;
        const int n4 = (M_TOT * K_TOT) / 4;
        for (int i = idx; i < n4; i += 2048 * 256) {
            float4 f = reinterpret_cast<const float4*>(x)[i];
            union { bf16 h[4]; uint64_t u; } pk;
            pk.h[0] = (bf16)f.x; pk.h[1] = (bf16)f.y; pk.h[2] = (bf16)f.z; pk.h[3] = (bf16)f.w;
            reinterpret_cast<uint64_t*>(xb)[i] = pk.u;
        }
    } else {
        __shared__ float tile[32][33];
        int bid = blockIdx.x - 2048;
        int tn = bid % (N_TOT/32);
        int ti = bid / (N_TOT/32);
        int tid = threadIdx.x;
        int c = tid & 31, rgrp = tid >> 5;
        #pragma unroll
        for (int p = 0; p < 4; ++p) {
            int il = p * 8 + rgrp;
            int cn = tn*32 + c;                      // permuted output col
            int h = cn >> 7, k2 = (cn >> 6) & 1, d = cn & 63;
            int nsrc = (h << 7) + (d << 1) + k2;     // original col
            tile[il][c] = w[(ti*32 + il) * N_TOT + nsrc];
        }
        __syncthreads();
        #pragma unroll
        for (int p = 0; p < 4; ++p) {
            int nl = p * 8 + rgrp;
            wt[(size_t)(tn*32 + nl) * K_TOT + ti*32 + c] = (bf16)tile[c][nl];
        }
    }
}

// ---------------- pass 1: GEMM + silu + fused score; stores only v (bf16) and s (fp32) ----------------
// 256x128 tile (one head per block), BK=64, 3 LDS buffers, counted vmcnt(6) at tile end.
// 8 waves as 4M x 2N; per-wave 64x64; wn=0 -> k-half (score only), wn=1 -> v-half (store).
__device__ __forceinline__ bf16x8 frag(const bf16* base, int row, int slot) {
    const char* p = (const char*)base + row * 128 + (((slot ^ (row & 7)) & 7) << 4);
    return *reinterpret_cast<const bf16x8*>(p);
}

__global__ __launch_bounds__(512, 2)
void k_gemm(const bf16* __restrict__ xb, const bf16* __restrict__ wt,
            const float* __restrict__ q, bf16* __restrict__ v, float* __restrict__ s) {
    extern __shared__ __attribute__((aligned(16))) char smem[];
    bf16* lds = (bf16*)smem;   // 3 buffers of BUF_ELEMS

    const int tid = threadIdx.x;
    const int wid = tid >> 6, lane = tid & 63;
    const int wm = wid >> 1, wn = wid & 1;
    const int g = lane >> 4, r16 = lane & 15;

    // XCD swizzle: 1024 blocks, 128 contiguous per XCD
    int bid = blockIdx.x;
    int swz = (bid & 7) * 128 + (bid >> 3);
    int bm = swz >> 4, bn = swz & 15;
    const int row0 = bm * BM;
    const int n0 = bn * BN;
    const int h = bn;              // head index

    auto stageA = [&](int bi, int t) {
        bf16* dst = lds + bi * BUF_ELEMS;
        int k0 = t * BK;
        #pragma unroll
        for (int j = 0; j < 4; ++j) {
            int c = j * 512 + tid;
            int row = c >> 3, p = c & 7;
            gld_lds16(xb + (size_t)(row0 + row) * K_TOT + k0 + ((p ^ (row & 7)) << 3), dst + c * 8);
        }
    };
    auto stageB = [&](int bi, int t) {
        bf16* dst = lds + bi * BUF_ELEMS + BM * BK;
        int k0 = t * BK;
        #pragma unroll
        for (int j = 0; j < 2; ++j) {
            int c = j * 512 + tid;
            int row = c >> 3, p = c & 7;
            gld_lds16(wt + (size_t)(n0 + row) * K_TOT + k0 + ((p ^ (row & 7)) << 3), dst + c * 8);
        }
    };

    f32x4 acc[4][4];
    #pragma unroll
    for (int i = 0; i < 4; ++i)
        #pragma unroll
        for (int j = 0; j < 4; ++j) acc[i][j] = (f32x4){0.f,0.f,0.f,0.f};

    // prologue: stage tiles 0 and 1; wait only for tile 0 (vmcnt(6) leaves tile 1 in flight)
    stageA(0, 0); stageB(0, 0);
    stageA(1, 1); stageB(1, 1);
    asm volatile("s_waitcnt vmcnt(6)" ::: "memory");
    __builtin_amdgcn_s_barrier();

    #pragma unroll 1
    for (int t = 0; t < NT; ++t) {
        const int cur = t % 3;
        const int nx2 = (t + 2) % 3;
        const bf16* Ab = lds + cur * BUF_ELEMS;
        const bf16* Bb = Ab + BM * BK;
        const bool st = (t + 2 < NT);
        bf16x8 a[4], b[4];

        // ---- P0: ks=0 ----
        #pragma unroll
        for (int mi = 0; mi < 4; ++mi) a[mi] = frag(Ab, wm*64 + mi*16 + r16, g);
        #pragma unroll
        for (int ni = 0; ni < 4; ++ni) b[ni] = frag(Bb, wn*64 + ni*16 + r16, g);
        if (st) stageA(nx2, t + 2);
        __builtin_amdgcn_s_barrier();
        __builtin_amdgcn_s_setprio(1);
        #pragma unroll
        for (int mi = 0; mi < 4; ++mi)
            #pragma unroll
            for (int ni = 0; ni < 4; ++ni)
                acc[mi][ni] = __builtin_amdgcn_mfma_f32_16x16x32_bf16(a[mi], b[ni], acc[mi][ni], 0,0,0);
        __builtin_amdgcn_s_setprio(0);
        __builtin_amdgcn_s_barrier();

        // ---- P1: ks=1 ----
        #pragma unroll
        for (int mi = 0; mi < 4; ++mi) a[mi] = frag(Ab, wm*64 + mi*16 + r16, 4 + g);
        #pragma unroll
        for (int ni = 0; ni < 4; ++ni) b[ni] = frag(Bb, wn*64 + ni*16 + r16, 4 + g);
        if (st) stageB(nx2, t + 2);
        __builtin_amdgcn_s_barrier();
        __builtin_amdgcn_s_setprio(1);
        #pragma unroll
        for (int mi = 0; mi < 4; ++mi)
            #pragma unroll
            for (int ni = 0; ni < 4; ++ni)
                acc[mi][ni] = __builtin_amdgcn_mfma_f32_16x16x32_bf16(a[mi], b[ni], acc[mi][ni], 0,0,0);
        __builtin_amdgcn_s_setprio(0);
        if (t + 1 < NT) {
            if (st) asm volatile("s_waitcnt vmcnt(6)" ::: "memory");
            else    asm volatile("s_waitcnt vmcnt(0)" ::: "memory");
            __builtin_amdgcn_s_barrier();
        }
    }

    // ---- epilogue ----
    if (wn == 0) {
        // k-half: score s[row,h] = sum_d silu(k)*q[h,d]; k never stored
        float qv[4];
        #pragma unroll
        for (int ni = 0; ni < 4; ++ni) qv[ni] = q[h * D_ + ni*16 + r16];
        #pragma unroll
        for (int mi = 0; mi < 4; ++mi) {
            #pragma unroll
            for (int r = 0; r < 4; ++r) {
                float part = 0.f;
                #pragma unroll
                for (int ni = 0; ni < 4; ++ni) {
                    float x = acc[mi][ni][r];
                    part += (x / (1.0f + __expf(-x))) * qv[ni];
                }
                part += __shfl_xor(part, 1);
                part += __shfl_xor(part, 2);
                part += __shfl_xor(part, 4);
                part += __shfl_xor(part, 8);
                if (r16 == 0) {
                    int row = row0 + wm*64 + mi*16 + g*4 + r;
                    s[row * H_ + h] = part;
                }
            }
        }
    } else {
        // v-half: silu + store bf16 to v[row][h*64+d]
        #pragma unroll
        for (int mi = 0; mi < 4; ++mi)
            #pragma unroll
            for (int ni = 0; ni < 4; ++ni)
                #pragma unroll
                for (int r = 0; r < 4; ++r) {
                    int row = row0 + wm*64 + mi*16 + g*4 + r;
                    int d = ni*16 + r16;
                    float x = acc[mi][ni][r];
                    v[(size_t)row * (H_*D_) + h*D_ + d] = (bf16)(x / (1.0f + __expf(-x)));
                }
    }
}

// ---------------- scan: 64 chunks of 64 per (b,h); one wave per chunk, lane = d ----------------
__global__ void k_scanA(const float* __restrict__ s, const bf16* __restrict__ v, float* __restrict__ agg) {
    int C = blockIdx.x * 4 + (threadIdx.x >> 6);
    int lane = threadIdx.x & 63;
    int p = C >> 6, c = C & 63;
    int b = p >> 4, h = p & 15;
    int rbase = b * T_ + c * 64;
    const bf16* vbase = v + h * D_ + lane;
    float m = -INFINITY, u = 0.f, w = 0.f;
    #pragma unroll 4
    for (int i = 0; i < 64; ++i) {
        int r = rbase + i;
        float sv = s[r * H_ + h];
        float vv = (float)vbase[(size_t)r * (H_*D_)];
        float mn = fmaxf(m, sv);
        float ea = __expf(m - mn);
        float eb = __expf(sv - mn);
        u = u * ea + eb;
        w = w * ea + vv * eb;
        m = mn;
    }
    float* a = agg + C * 66;
    if (lane == 0) { a[0] = m; a[1] = u; }
    a[2 + lane] = w;
}

// Phase B: exclusive scan over 64 chunk aggregates per (b,h); all data preloaded to registers
__global__ void k_scanB(const float* __restrict__ agg, float* __restrict__ pre) {
    int p = blockIdx.x;       // 0..63
    int lane = threadIdx.x;   // 0..63
    float wreg[64];
    #pragma unroll
    for (int c = 0; c < 64; ++c) wreg[c] = agg[(size_t)(p*64 + c)*66 + 2 + lane];
    float ml = agg[(size_t)(p*64 + lane)*66];
    float ul = agg[(size_t)(p*64 + lane)*66 + 1];
    float m = -INFINITY, u = 0.f, w = 0.f;
    #pragma unroll
    for (int c = 0; c < 64; ++c) {
        float* o = pre + (size_t)(p*64 + c)*66;
        if (lane == 0) { o[0] = m; o[1] = u; }
        o[2 + lane] = w;
        float ma = __shfl(ml, c), ua = __shfl(ul, c), wa = wreg[c];
        float mn = fmaxf(m, ma);
        float ec = __expf(m - mn), ea = __expf(ma - mn);
        u = u * ec + ua * ea;
        w = w * ec + wa * ea;
        m = mn;
    }
}

__global__ void k_scanC(const float* __restrict__ s, const bf16* __restrict__ v,
                        const float* __restrict__ pre, float* __restrict__ out) {
    int C = blockIdx.x * 4 + (threadIdx.x >> 6);
    int lane = threadIdx.x & 63;
    int p = C >> 6, c = C & 63;
    int b = p >> 4, h = p & 15;
    int rbase = b * T_ + c * 64;
    const bf16* vbase = v + h * D_ + lane;
    const float* pr = pre + C * 66;
    float m = pr[0], u = pr[1], w = pr[2 + lane];
    #pragma unroll 4
    for (int i = 0; i < 64; ++i) {
        int r = rbase + i;
        float sv = s[r * H_ + h];
        float vv = (float)vbase[(size_t)r * (H_*D_)];
        float mn = fmaxf(m, sv);
        float ea = __expf(m - mn);
        float eb = __expf(sv - mn);
        u = u * ea + eb;
        w = w * ea + vv * eb;
        m = mn;
        out[(size_t)r * (H_*D_) + h * D_ + lane] = __fdividef(w, u);
    }
}

extern "C" void kernel_launch(void* const* d_in, const int* in_sizes, int n_in,
                              void* d_out, int out_size, void* d_ws, size_t ws_size,
                              hipStream_t stream) {
    (void)in_sizes; (void)n_in; (void)out_size; (void)ws_size;
    const float* x  = (const float*)d_in[0];
    const float* wk = (const float*)d_in[1];
    const float* qk = (const float*)d_in[2];
    float* out = (float*)d_out;
    char* ws = (char*)d_ws;

    bf16*  xb  = (bf16*) (ws);                      // 33,554,432
    bf16*  wt  = (bf16*) (ws + 33554432ull);        //  4,194,304
    bf16*  v   = (bf16*) (ws + 37748736ull);        // 33,554,432
    float* s   = (float*)(ws + 71303168ull);        //  1,048,576
    float* agg = (float*)(ws + 72351744ull);        //  1,081,344
    float* pre = (float*)(ws + 73433088ull);        //  1,081,344

    hipLaunchKernelGGL(k_prep,  dim3(4096), dim3(256), 0, stream, x, wk, xb, wt);
    hipLaunchKernelGGL(k_gemm,  dim3((M_TOT/BM)*(N_TOT/BN)), dim3(512), 3*BUF_ELEMS*2, stream, xb, wt, qk, v, s);
    hipLaunchKernelGGL(k_scanA, dim3(B_*H_*64/4), dim3(256), 0, stream, s, v, agg);
    hipLaunchKernelGGL(k_scanB, dim3(B_*H_), dim3(64), 0, stream, agg, pre);
    hipLaunchKernelGGL(k_scanC, dim3(B_*H_*64/4), dim3(256), 0, stream, s, v, pre, out);
}

// Round 5
// 232.941 us; speedup vs baseline: 1.2520x; 1.0444x over previous
//
#include <hip/hip_runtime.h>
#include <hip/hip_bf16.h>
#include <stdint.h>

// Problem constants
#define B_ 4
#define T_ 4096
#define I_ 1024
#define H_ 16
#define D_ 64
#define M_TOT (B_*T_)      // 16384
#define N_TOT (H_*D_*2)    // 2048, permuted: col = h*128 + k2*64 + d
#define K_TOT I_           // 1024

#define BM 256
#define BN 256
#define BK 32
#define NT (K_TOT/BK)               // 32
#define BUFE (BM*BK + BN*BK)        // 16384 elems = 32 KB per buffer

typedef __bf16 bf16;
typedef __attribute__((ext_vector_type(8))) __bf16 bf16x8;
typedef __attribute__((ext_vector_type(4))) float f32x4;

#define AS_G __attribute__((address_space(1)))
#define AS_L __attribute__((address_space(3)))

__device__ __forceinline__ void gld_lds16(const void* g, void* l) {
    __builtin_amdgcn_global_load_lds((const AS_G void*)g, (AS_L void*)l, 16, 0, 0);
}

// ---------------- pass 0: fused convert: X fp32->bf16 ; W (I,N) -> Wt (N',I) bf16 permuted ----------------
__global__ void k_prep(const float* __restrict__ x, const float* __restrict__ w,
                       bf16* __restrict__ xb, bf16* __restrict__ wt) {
    if (blockIdx.x < 2048) {
        int idx = blockIdx.x * 256 + threadIdx.x;
        const int n4 = (M_TOT * K_TOT) / 4;
        for (int i = idx; i < n4; i += 2048 * 256) {
            float4 f = reinterpret_cast<const float4*>(x)[i];
            union { bf16 h[4]; uint64_t u; } pk;
            pk.h[0] = (bf16)f.x; pk.h[1] = (bf16)f.y; pk.h[2] = (bf16)f.z; pk.h[3] = (bf16)f.w;
            reinterpret_cast<uint64_t*>(xb)[i] = pk.u;
        }
    } else {
        __shared__ float tile[32][33];
        int bid = blockIdx.x - 2048;
        int tn = bid % (N_TOT/32);
        int ti = bid / (N_TOT/32);
        int tid = threadIdx.x;
        int c = tid & 31, rgrp = tid >> 5;
        #pragma unroll
        for (int p = 0; p < 4; ++p) {
            int il = p * 8 + rgrp;
            int cn = tn*32 + c;                      // permuted output col
            int h = cn >> 7, k2 = (cn >> 6) & 1, d = cn & 63;
            int nsrc = (h << 7) + (d << 1) + k2;     // original col
            tile[il][c] = w[(ti*32 + il) * N_TOT + nsrc];
        }
        __syncthreads();
        #pragma unroll
        for (int p = 0; p < 4; ++p) {
            int nl = p * 8 + rgrp;
            wt[(size_t)(tn*32 + nl) * K_TOT + ti*32 + c] = (bf16)tile[c][nl];
        }
    }
}

// ---------------- pass 1: GEMM + silu + fused score + fused chunk-aggregates ----------------
// 256x256 tile, BK=32, 4 LDS buffers, counted vmcnt(8), 8 waves (2M x 4N), per-wave 128x64.
// LDS row = 64B (4 slots of 16B); slot swizzle: sl' = sl ^ ((row>>1)&3).
__device__ __forceinline__ bf16x8 frag(const bf16* base, int row, int g) {
    const char* p = (const char*)base + row * 64 + (((g ^ ((row >> 1) & 3)) & 3) << 4);
    return *reinterpret_cast<const bf16x8*>(p);
}

__global__ __launch_bounds__(512, 2)
void k_gemm(const bf16* __restrict__ xb, const bf16* __restrict__ wt,
            const float* __restrict__ q, bf16* __restrict__ v,
            float* __restrict__ s, float* __restrict__ agg) {
    extern __shared__ __attribute__((aligned(16))) char smem[];
    bf16* lds = (bf16*)smem;                       // 4 * BUFE elems
    float* s_lds = (float*)(smem + 4*BUFE*2);      // [2][256]

    const int tid = threadIdx.x;
    const int wid = tid >> 6, lane = tid & 63;
    const int wm = wid >> 2, wn = wid & 3;
    const int g = lane >> 4, r16 = lane & 15;

    // XCD swizzle: 512 blocks, 64 contiguous per XCD
    int bid = blockIdx.x;
    int swz = (bid & 7) * 64 + (bid >> 3);
    int bm = swz >> 3, bn = swz & 7;
    const int row0 = bm * BM, n0 = bn * BN;

    auto stageA = [&](int t) {
        bf16* dst = lds + (t & 3) * BUFE;
        int k0 = t * BK;
        #pragma unroll
        for (int j = 0; j < 2; ++j) {
            int c = j * 512 + tid;
            int row = c >> 2, sl = c & 3;
            int koff = ((sl ^ ((row >> 1) & 3)) & 3) << 3;
            gld_lds16(xb + (size_t)(row0 + row) * K_TOT + k0 + koff, (char*)dst + c * 16);
        }
    };
    auto stageB = [&](int t) {
        bf16* dst = lds + (t & 3) * BUFE + BM * BK;
        int k0 = t * BK;
        #pragma unroll
        for (int j = 0; j < 2; ++j) {
            int c = j * 512 + tid;
            int row = c >> 2, sl = c & 3;
            int koff = ((sl ^ ((row >> 1) & 3)) & 3) << 3;
            gld_lds16(wt + (size_t)(n0 + row) * K_TOT + k0 + koff, (char*)dst + c * 16);
        }
    };

    f32x4 acc[8][4];
    #pragma unroll
    for (int i = 0; i < 8; ++i)
        #pragma unroll
        for (int j = 0; j < 4; ++j) acc[i][j] = (f32x4){0.f,0.f,0.f,0.f};

    // prologue: tiles 0,1,2 staged (12 loads/thread); drain tile 0 only
    stageA(0); stageB(0);
    stageA(1); stageB(1);
    stageA(2); stageB(2);
    asm volatile("s_waitcnt vmcnt(8)" ::: "memory");
    __builtin_amdgcn_s_barrier();

    #pragma unroll 1
    for (int t = 0; t < NT; ++t) {
        const bf16* Ab = lds + (t & 3) * BUFE;
        const bf16* Bb = Ab + BM * BK;
        const bool st = (t + 3 < NT);
        bf16x8 a[4], b[4];

        // ---- P0: mi 0-3 ----
        #pragma unroll
        for (int mi = 0; mi < 4; ++mi) a[mi] = frag(Ab, wm*128 + mi*16 + r16, g);
        #pragma unroll
        for (int ni = 0; ni < 4; ++ni) b[ni] = frag(Bb, wn*64 + ni*16 + r16, g);
        if (st) stageA(t + 3);
        __builtin_amdgcn_s_barrier();
        __builtin_amdgcn_s_setprio(1);
        #pragma unroll
        for (int mi = 0; mi < 4; ++mi)
            #pragma unroll
            for (int ni = 0; ni < 4; ++ni)
                acc[mi][ni] = __builtin_amdgcn_mfma_f32_16x16x32_bf16(a[mi], b[ni], acc[mi][ni], 0,0,0);
        __builtin_amdgcn_s_setprio(0);
        __builtin_amdgcn_s_barrier();

        // ---- P1: mi 4-7 (b reused) ----
        #pragma unroll
        for (int mi = 0; mi < 4; ++mi) a[mi] = frag(Ab, wm*128 + (mi+4)*16 + r16, g);
        if (st) stageB(t + 3);
        __builtin_amdgcn_s_barrier();
        __builtin_amdgcn_s_setprio(1);
        #pragma unroll
        for (int mi = 0; mi < 4; ++mi)
            #pragma unroll
            for (int ni = 0; ni < 4; ++ni)
                acc[mi+4][ni] = __builtin_amdgcn_mfma_f32_16x16x32_bf16(a[mi], b[ni], acc[mi+4][ni], 0,0,0);
        __builtin_amdgcn_s_setprio(0);
        if (t < NT - 1) {
            if (t < NT - 3)       asm volatile("s_waitcnt vmcnt(8)" ::: "memory");
            else if (t == NT - 3) asm volatile("s_waitcnt vmcnt(4)" ::: "memory");
            else                  asm volatile("s_waitcnt vmcnt(0)" ::: "memory");
            __builtin_amdgcn_s_barrier();
        }
    }

    // ---- epilogue: silu all acc in place ----
    #pragma unroll
    for (int mi = 0; mi < 8; ++mi)
        #pragma unroll
        for (int ni = 0; ni < 4; ++ni)
            #pragma unroll
            for (int r = 0; r < 4; ++r) {
                float x = acc[mi][ni][r];
                acc[mi][ni][r] = x / (1.0f + __expf(-x));
            }

    const int hloc = wn >> 1;
    const int h = bn * 2 + hloc;

    if ((wn & 1) == 0) {
        // k-wave: score s[row,h] = sum_d silu(k)*q[h,d]
        float qv[4];
        #pragma unroll
        for (int ni = 0; ni < 4; ++ni) qv[ni] = q[h * D_ + ni*16 + r16];
        #pragma unroll
        for (int mi = 0; mi < 8; ++mi) {
            #pragma unroll
            for (int r = 0; r < 4; ++r) {
                float part = acc[mi][0][r]*qv[0] + acc[mi][1][r]*qv[1]
                           + acc[mi][2][r]*qv[2] + acc[mi][3][r]*qv[3];
                part += __shfl_xor(part, 1);
                part += __shfl_xor(part, 2);
                part += __shfl_xor(part, 4);
                part += __shfl_xor(part, 8);
                if (r16 == 0) {
                    int rl = wm*128 + mi*16 + g*4 + r;
                    s[(row0 + rl) * H_ + h] = part;
                    s_lds[hloc*256 + rl] = part;
                }
            }
        }
    } else {
        // v-wave: store silu'd v as bf16
        #pragma unroll
        for (int mi = 0; mi < 8; ++mi)
            #pragma unroll
            for (int ni = 0; ni < 4; ++ni)
                #pragma unroll
                for (int r = 0; r < 4; ++r) {
                    int row = row0 + wm*128 + mi*16 + g*4 + r;
                    v[(size_t)row * (H_*D_) + h*D_ + ni*16 + r16] = (bf16)acc[mi][ni][r];
                }
    }
    __syncthreads();

    if (wn & 1) {
        // chunk aggregates: wave covers 128 rows = 2 chunks of 64
        #pragma unroll
        for (int c = 0; c < 2; ++c) {
            float sv[16];
            #pragma unroll
            for (int mm = 0; mm < 4; ++mm)
                #pragma unroll
                for (int r = 0; r < 4; ++r)
                    sv[mm*4+r] = s_lds[hloc*256 + wm*128 + (c*4+mm)*16 + g*4 + r];
            float m_l = sv[0];
            #pragma unroll
            for (int i = 1; i < 16; ++i) m_l = fmaxf(m_l, sv[i]);
            float u_l = 0.f, w_l[4] = {0.f, 0.f, 0.f, 0.f};
            #pragma unroll
            for (int mm = 0; mm < 4; ++mm)
                #pragma unroll
                for (int r = 0; r < 4; ++r) {
                    float e = __expf(sv[mm*4+r] - m_l);
                    u_l += e;
                    #pragma unroll
                    for (int ni = 0; ni < 4; ++ni)
                        w_l[ni] += e * acc[c*4+mm][ni][r];
                }
            // combine across the 4 g-groups (lanes xor 16, 32)
            #pragma unroll
            for (int off = 16; off <= 32; off <<= 1) {
                float m2 = __shfl_xor(m_l, off);
                float u2 = __shfl_xor(u_l, off);
                float w2[4];
                #pragma unroll
                for (int ni = 0; ni < 4; ++ni) w2[ni] = __shfl_xor(w_l[ni], off);
                float mn = fmaxf(m_l, m2);
                float ea = __expf(m_l - mn), eb = __expf(m2 - mn);
                u_l = u_l * ea + u2 * eb;
                #pragma unroll
                for (int ni = 0; ni < 4; ++ni) w_l[ni] = w_l[ni]*ea + w2[ni]*eb;
                m_l = mn;
            }
            if (g == 0) {
                int rbase = row0 + wm*128 + c*64;
                int bb = rbase >> 12, tloc = rbase & (T_-1);
                float* a = agg + (size_t)(((bb*H_ + h) << 6) + (tloc >> 6)) * 66;
                if (r16 == 0) { a[0] = m_l; a[1] = u_l; }
                #pragma unroll
                for (int ni = 0; ni < 4; ++ni) a[2 + ni*16 + r16] = w_l[ni];
            }
        }
    }
}

// ---------------- scan phase B: exclusive scan over 64 chunk aggregates per (b,h) ----------------
__global__ void k_scanB(const float* __restrict__ agg, float* __restrict__ pre) {
    int p = blockIdx.x;       // 0..63
    int lane = threadIdx.x;   // 0..63
    float wreg[64];
    #pragma unroll
    for (int c = 0; c < 64; ++c) wreg[c] = agg[(size_t)(p*64 + c)*66 + 2 + lane];
    float ml = agg[(size_t)(p*64 + lane)*66];
    float ul = agg[(size_t)(p*64 + lane)*66 + 1];
    float m = -INFINITY, u = 0.f, w = 0.f;
    #pragma unroll
    for (int c = 0; c < 64; ++c) {
        float* o = pre + (size_t)(p*64 + c)*66;
        if (lane == 0) { o[0] = m; o[1] = u; }
        o[2 + lane] = w;
        float ma = __shfl(ml, c), ua = __shfl(ul, c), wa = wreg[c];
        float mn = fmaxf(m, ma);
        float ec = __expf(m - mn), ea = __expf(ma - mn);
        u = u * ec + ua * ea;
        w = w * ec + wa * ea;
        m = mn;
    }
}

// ---------------- scan phase C: local rescan with carry-in; out = w/u ----------------
__global__ void k_scanC(const float* __restrict__ s, const bf16* __restrict__ v,
                        const float* __restrict__ pre, float* __restrict__ out) {
    int C = blockIdx.x * 4 + (threadIdx.x >> 6);
    int lane = threadIdx.x & 63;
    int p = C >> 6, c = C & 63;
    int b = p >> 4, h = p & 15;
    int rbase = b * T_ + c * 64;
    const bf16* vbase = v + h * D_ + lane;
    const float* pr = pre + C * 66;
    float m = pr[0], u = pr[1], w = pr[2 + lane];
    #pragma unroll 4
    for (int i = 0; i < 64; ++i) {
        int r = rbase + i;
        float sv = s[r * H_ + h];
        float vv = (float)vbase[(size_t)r * (H_*D_)];
        float mn = fmaxf(m, sv);
        float ea = __expf(m - mn);
        float eb = __expf(sv - mn);
        u = u * ea + eb;
        w = w * ea + vv * eb;
        m = mn;
        out[(size_t)r * (H_*D_) + h * D_ + lane] = __fdividef(w, u);
    }
}

extern "C" void kernel_launch(void* const* d_in, const int* in_sizes, int n_in,
                              void* d_out, int out_size, void* d_ws, size_t ws_size,
                              hipStream_t stream) {
    (void)in_sizes; (void)n_in; (void)out_size; (void)ws_size;
    const float* x  = (const float*)d_in[0];
    const float* wk = (const float*)d_in[1];
    const float* qk = (const float*)d_in[2];
    float* out = (float*)d_out;
    char* ws = (char*)d_ws;

    bf16*  xb  = (bf16*) (ws);                      // 33,554,432
    bf16*  wt  = (bf16*) (ws + 33554432ull);        //  4,194,304
    bf16*  v   = (bf16*) (ws + 37748736ull);        // 33,554,432
    float* s   = (float*)(ws + 71303168ull);        //  1,048,576
    float* agg = (float*)(ws + 72351744ull);        //  1,081,344
    float* pre = (float*)(ws + 73433088ull);        //  1,081,344

    hipLaunchKernelGGL(k_prep,  dim3(4096), dim3(256), 0, stream, x, wk, xb, wt);
    hipLaunchKernelGGL(k_gemm,  dim3((M_TOT/BM)*(N_TOT/BN)), dim3(512), 4*BUFE*2 + 2048, stream,
                       xb, wt, qk, v, s, agg);
    hipLaunchKernelGGL(k_scanB, dim3(B_*H_), dim3(64), 0, stream, agg, pre);
    hipLaunchKernelGGL(k_scanC, dim3(B_*H_*64/4), dim3(256), 0, stream, s, v, pre, out);
}